// Round 8
// baseline (19818.658 us; speedup 1.0000x reference)
//
#include <hip/hip_runtime.h>
#include <hip/hip_bf16.h>
#include <stdint.h>

// ---------------------------------------------------------------------------
// DiffusionModel: 100 fused steps of x <- x + B*(x@Wx + t*csum + b) + s*noise
// R12: occupancy push, attempt 3 -- with the register law learned from
// R10/R11: (1024,8) splits to ~32 arch VGPRs (spill: R11 VALU-busy ROSE to
// 5.8ms); 1024-thr blocks are locked to 4 w/SIMD. Path to 6 w/SIMD is
// 512-thr blocks x 3 resident/CU at (512,6)=85 regs, with live shrunk to
// ~64: block owns 16 ROWS (16 elems/thread), acc 4 (one 16x16 tile/sweep),
// xr 16. R10 failed this budget at ~110 live; now ~64 -> real margin.
// Three independent barrier domains per CU desynchronize -> VALU fill.
// Kept from R9 (proven): RNG folded into K-sweep (here at c%4==1, 4 elems
// per nt-sweep), rolling depth-2 W prefetch with t-invariant periodic
// addresses (64-position stream nt0c0..15,..,nt3c0..15), double-buffered
// xs (1 barrier/step), packed bf16 image writes.
// Memory note (R11): FETCH ~= full blob demand at ~50% L2 hit, served by
// 256MB LLC at ~3TB/s aggregate -- latency covered by prefetch+RNG cover;
// more blocks re-reading the blob is NOT a wall.
//
// REGISTER MODEL (R2-R11 measured): budget = 512/launch_bounds_arg2, VGPR+
// AGPR unified; arch side lands near budget/2 when AGPR-pressured. Spill
// symptom: VGPR_Count ~halved + WRITE_SIZE in GBs (R6 3.6, R10 39, R11 0.7).
// This config: arch ~40-48 + agpr ~24 <= 85. Alarm -> revert to R9.
// ---------------------------------------------------------------------------

typedef __attribute__((ext_vector_type(8))) short short8;
typedef __attribute__((ext_vector_type(4))) float f32x4;

#define XS_STRIDE 520          // bf16 elems per x-row in LDS (512+8 pad)
#define NSTEP 100

// Threefry-2x32, 20 rounds, exactly as jax._src.prng.threefry2x32
__device__ __forceinline__ void tf_rounds(uint32_t k0, uint32_t k1, uint32_t k2,
                                          uint32_t& a, uint32_t& b) {
  a += k0; b += k1;
#define TFR(r) { a += b; b = __builtin_rotateleft32(b, (r)); b ^= a; }
  TFR(13) TFR(15) TFR(26) TFR(6)   a += k1; b += k2 + 1u;
  TFR(17) TFR(29) TFR(16) TFR(24)  a += k2; b += k0 + 2u;
  TFR(13) TFR(15) TFR(26) TFR(6)   a += k0; b += k1 + 3u;
  TFR(17) TFR(29) TFR(16) TFR(24)  a += k1; b += k2 + 4u;
  TFR(13) TFR(15) TFR(26) TFR(6)   a += k2; b += k0 + 5u;
#undef TFR
}

// bits -> uniform[-0.99999994, 1) -> sqrt(2)*erfinv(u)  (XLA/Giles erfinv).
// Bit-identical to R5-R11 (RNG must match the JAX reference).
__device__ __forceinline__ float gauss_from_bits(uint32_t bits) {
  const float lo = __uint_as_float(0xBF7FFFFFu);   // nextafter(-1,0)
  float f = __uint_as_float((bits >> 9) | 0x3F800000u) - 1.0f;  // [0,1)
  float u = fmaxf(lo, fmaf(f, 2.0f, lo));
  float om = fmaf(u, -u, 1.0f);                    // 1-u^2 > 0
  float L = __log2f(om);                           // w = -ln2 * L
  float p;
  if (__builtin_expect(L > -7.2134752f, 1)) {      // w < 5
    float z = fmaf(-0.69314718f, L, -2.5f);        // w - 2.5
    p =            2.81022636e-08f;
    p = fmaf(p, z, 3.43273939e-07f);
    p = fmaf(p, z, -3.5233877e-06f);
    p = fmaf(p, z, -4.39150654e-06f);
    p = fmaf(p, z, 0.00021858087f);
    p = fmaf(p, z, -0.00125372503f);
    p = fmaf(p, z, -0.00417768164f);
    p = fmaf(p, z, 0.246640727f);
    p = fmaf(p, z, 1.50140941f);
  } else {
    float z = sqrtf(-0.69314718f * L) - 3.0f;
    p =            -0.000200214257f;
    p = fmaf(p, z, 0.000100950558f);
    p = fmaf(p, z, 0.00134934322f);
    p = fmaf(p, z, -0.00367342844f);
    p = fmaf(p, z, 0.00573950773f);
    p = fmaf(p, z, -0.0076224613f);
    p = fmaf(p, z, 0.00943887047f);
    p = fmaf(p, z, 1.00167406f);
    p = fmaf(p, z, 2.83297682f);
  }
  return 1.41421356f * (p * u);   // sqrt(2) * erfinv(u)
}

// f32 -> bf16 RNE (bit trick) — prep kernel only
__device__ __forceinline__ uint16_t f2bf(float f) {
  uint32_t u = __float_as_uint(f);
  u += 0x7FFFu + ((u >> 16) & 1u);
  return (uint16_t)(u >> 16);
}

// packed pair f32x2 -> bf16x2 (v_cvt_pk_bf16_f32; RNE == bit-trick on
// normal values, which is all x ever is here)
__device__ __forceinline__ uint32_t f2bf_pk(float lo, float hi) {
  union { __hip_bfloat162 h; uint32_t u; } cv;
  cv.h = __float22bfloat162_rn(make_float2(lo, hi));
  return cv.u;
}

// --------------------------------------------------------------------------
// Pre-pass 1: Wx (rows 0..511 of W) -> bf16 blob, UNPADDED [c][n][32]:
// chunk c holds k in [32c,32c+32); B-frag for (c,n,q) = 16B at n*64+q*16 B.
// --------------------------------------------------------------------------
__global__ void prep_w_kernel(const float* __restrict__ W, uint16_t* __restrict__ blob) {
  int id = blockIdx.x * 256 + threadIdx.x;
  if (id >= 512 * 512) return;
  int k = id >> 9;        // feature (K) index
  int n = id & 511;       // output col
  float v = W[k * 512 + n];
  int c = k >> 5, kk = k & 31;
  blob[c * 16384 + n * 32 + kk] = f2bf(v);
}

// Pre-pass 2: csum[n] = sum_j W[512+j][n]  (rank-1 t-embedding part)
__global__ void prep_csum_kernel(const float* __restrict__ W, float* __restrict__ csum) {
  int n = blockIdx.x * 256 + threadIdx.x;
  if (n >= 512) return;
  float s = 0.0f;
  for (int j = 0; j < 512; ++j) s += W[(512 + j) * 512 + n];
  csum[n] = s;
}

// --------------------------------------------------------------------------
// Main fused kernel. MFMA 16x16x32 bf16: A[m=lane&15][k=q*8+j] (from xs),
// B[k][n=lane&15] (direct global 16B coalesced load), C row=4q+reg.
// Block (512 thr, 8 waves) owns rows [16b, 16b+16); wave w covers cols
// [64w, 64w+64): nt in 0..3, four K-sweeps of 16 chunks, 1 MFMA per chunk,
// RNG for element j=c>>2 interleaved at c%4==1. xs double-buffered,
// 1 barrier/step. W prefetch: rolling depth-2 over the 64-position stream
// p=nt*16+c -> uint16 offset (p&15)*16384+(p>>4)*512 (t-invariant, wraps
// across steps).
// --------------------------------------------------------------------------
__global__ __launch_bounds__(512, 6) void diffuse_kernel(
    const float* __restrict__ x0, const uint16_t* __restrict__ wblob,
    const float* __restrict__ csum, const float* __restrict__ bvec,
    float* __restrict__ out) {
  __shared__ alignas(16) uint16_t xs[2][16 * XS_STRIDE];  // 2 x 16640 B
  __shared__ alignas(8) float2 cb[512];                   // 4096 B {csum, bias}

  const int tid = threadIdx.x;     // 0..511
  const int l15 = tid & 15;
  const int q   = (tid >> 4) & 3;
  const int wv  = tid >> 6;        // wave 0..7
  const int blk = blockIdx.x;      // 0..2047

  cb[tid] = make_float2(csum[tid], bvec[tid]);

  int ncol[4];
#pragma unroll
  for (int nt = 0; nt < 4; ++nt)
    ncol[nt] = wv * 64 + nt * 16 + l15;

  // fp32 master of x, C-layout: nt[j] = local row 4q+j, col ncol[nt]
  f32x4 xr[4];
#pragma unroll
  for (int nt = 0; nt < 4; ++nt)
#pragma unroll
    for (int j = 0; j < 4; ++j)
      xr[nt][j] = x0[(blk * 16 + q * 4 + j) * 512 + ncol[nt]];

  // initial bf16 image into buffer 0 (packed pairs: rows m, m+1)
#pragma unroll
  for (int nt = 0; nt < 4; ++nt)
#pragma unroll
    for (int jj = 0; jj < 2; ++jj) {
      int m = q * 4 + jj * 2;
      uint32_t pk = f2bf_pk(xr[nt][jj * 2], xr[nt][jj * 2 + 1]);
      xs[0][m * XS_STRIDE + ncol[nt]] = (uint16_t)pk;
      xs[0][(m + 1) * XS_STRIDE + ncol[nt]] = (uint16_t)(pk >> 16);
    }

  const float sq2b = sqrtf(0.02f);   // sqrt(2*beta)
  const f32x4 vzero = {0.0f, 0.0f, 0.0f, 0.0f};

  // W stream base: fragment (c, n=ncol[nt], q) at uint16 offset
  // c*16384 + ncol[nt]*32 + q*8 = (p&15)*16384 + (p>>4)*512 + wbase_off.
  const uint16_t* wbase = wblob + (wv * 2048 + l15 * 32 + q * 8);
  short8 bf0 = *(const short8*)(wbase);
  short8 bf1 = *(const short8*)(wbase + 16384);

  __syncthreads();   // init image + cb visible to all waves

  for (int t = 0; t < NSTEP; ++t) {
    const uint16_t* xsc = xs[t & 1];
    uint16_t* xsn = xs[(t + 1) & 1];

    // key_t = fold_in(key(42), t) = threefry((0,42),(0,t))  [uniform -> SALU]
    uint32_t kt0 = 0u, kt1 = (uint32_t)t;
    tf_rounds(0u, 42u, 42u ^ 0x1BD11BDAu, kt0, kt1);
    const uint32_t kk2 = kt0 ^ kt1 ^ 0x1BD11BDAu;
    const float tf = (float)t;

#pragma unroll
    for (int nt = 0; nt < 4; ++nt) {
      f32x4 acc = vzero;
      const uint32_t base_e = (uint32_t)((blk * 16 + q * 4) * 512 + ncol[nt]);

      // ---- K sweep: 1 bf prefetch (depth-2, wraps) + 1 ds_read_b128 +
      //      1 MFMA per chunk; RNG chain for element j=c>>2 at c%4==1
      //      fills the load/dep stall slots ----
#pragma unroll
      for (int c = 0; c < 16; ++c) {
        const int p2 = (nt * 16 + c + 2) & 63;
        short8 bf2 = *(const short8*)(wbase + (p2 & 15) * 16384 + (p2 >> 4) * 512);
        short8 af = *(const short8*)&xsc[l15 * XS_STRIDE + c * 32 + q * 8];
        acc = __builtin_amdgcn_mfma_f32_16x16x32_bf16(af, bf0, acc, 0, 0, 0);
        if ((c & 3) == 1) {
          const int j = c >> 2;
          uint32_t a = 0u, b = base_e + (uint32_t)(j * 512);
          tf_rounds(kt0, kt1, kk2, a, b);
          float n = gauss_from_bits(a ^ b);
          xr[nt][j] = fmaf(sq2b, n, xr[nt][j]);   // x + s*noise
        }
        bf0 = bf1;
        bf1 = bf2;
      }

      // ---- short update: x += B*(acc + t*csum + b), pack, write image ----
      const float2 cbv = cb[ncol[nt]];
      const float tc = fmaf(tf, cbv.x, cbv.y);
#pragma unroll
      for (int j = 0; j < 4; ++j)
        xr[nt][j] = fmaf(0.01f, acc[j] + tc, xr[nt][j]);
      if (t + 1 < NSTEP) {
#pragma unroll
        for (int jj = 0; jj < 2; ++jj) {
          int m = q * 4 + jj * 2;
          uint32_t pk = f2bf_pk(xr[nt][jj * 2], xr[nt][jj * 2 + 1]);
          xsn[m * XS_STRIDE + ncol[nt]] = (uint16_t)pk;
          xsn[(m + 1) * XS_STRIDE + ncol[nt]] = (uint16_t)(pk >> 16);
        }
      }
    }

    if (t + 1 < NSTEP) __syncthreads();
  }

  // final store (fp32)
#pragma unroll
  for (int nt = 0; nt < 4; ++nt)
#pragma unroll
    for (int j = 0; j < 4; ++j)
      out[(blk * 16 + q * 4 + j) * 512 + ncol[nt]] = xr[nt][j];
}

extern "C" void kernel_launch(void* const* d_in, const int* in_sizes, int n_in,
                              void* d_out, int out_size, void* d_ws, size_t ws_size,
                              hipStream_t stream) {
  const float* x0 = (const float*)d_in[0];   // (32768, 512)
  const float* W  = (const float*)d_in[1];   // (1024, 512)
  const float* bv = (const float*)d_in[2];   // (512,)
  float* out = (float*)d_out;

  uint16_t* blob = (uint16_t*)d_ws;                     // 512 KB bf16 W-blob
  float* csum = (float*)((char*)d_ws + 16 * 16384 * 2); // +2 KB

  prep_w_kernel<<<dim3(1024), dim3(256), 0, stream>>>(W, blob);
  prep_csum_kernel<<<dim3(2), dim3(256), 0, stream>>>(W, csum);
  diffuse_kernel<<<dim3(2048), dim3(512), 0, stream>>>(x0, blob, csum, bv, out);
}

// Round 9
// 4899.363 us; speedup vs baseline: 4.0452x; 4.0452x over previous
//
#include <hip/hip_runtime.h>
#include <hip/hip_bf16.h>
#include <stdint.h>

// ---------------------------------------------------------------------------
// DiffusionModel: 100 fused steps of x <- x + B*(x@Wx + t*csum + b) + s*noise
// R13 = R9 structure (64 rows/block, nt-split sweeps w/ RNG interleave,
// depth-2 W prefetch, double-buffered xs, 1 barrier/step) with the matmul
// operands in FP8 E4M3 instead of bf16:
//  - W blob 512->256 KB, xs image 133->68 KB; fabric traffic (the R9 co-
//    bound: 11.8 GB ~= 4.1 ms at the measured ~2.5-2.9 TB/s LLC rate and
//    stubborn ~46% L2 miss rate seen in R5/R7/R9/R11/R12) halves to ~6 GB
//    ~= 2.1 ms -> fully hidden under the ~4.1 ms VALU stream.
//  - mfma_f32_16x16x32_fp8_fp8: same shape/C-layout/lane mapping as the
//    bf16 16x16x32 (k = q*8+j), A/B = 8 B/lane (ds_read_b64 -> LDS conflict
//    cycles halve).
//  - precision: x master stays fp32 in regs; e4m3 (1.8% RMS) only on matmul
//    operands -> accumulated error ~0.05 << 0.5 tolerance.
//  - __any-guarded erfinv slow path: 0.34%/lane -> 80% of waves skip it.
// R12 lesson (memory law): fabric ~= 0.46 * (32768/rows_block) * 51.2 MB;
// 16-row blocks -> 50 GB -> 20 ms. 64 rows is the LDS-feasible optimum.
//
// REGISTER MODEL (R2-R12): budget = 512/launch_bounds_arg2 = 128 at
// (1024,4). Live here: xr 16 + acc 8 (AGPR) + bf 6 + af 2 + RNG ~10 +
// addr ~12 => ~55-60, wide margin. Spill alarm: WRITE_SIZE >> 0.45 GB.
// ---------------------------------------------------------------------------

typedef __attribute__((ext_vector_type(4))) float f32x4;

#define XS_STRIDE 528          // bytes per x-row in LDS (512 + 16 pad)
#define NSTEP 100

// Threefry-2x32, 20 rounds, exactly as jax._src.prng.threefry2x32
__device__ __forceinline__ void tf_rounds(uint32_t k0, uint32_t k1, uint32_t k2,
                                          uint32_t& a, uint32_t& b) {
  a += k0; b += k1;
#define TFR(r) { a += b; b = __builtin_rotateleft32(b, (r)); b ^= a; }
  TFR(13) TFR(15) TFR(26) TFR(6)   a += k1; b += k2 + 1u;
  TFR(17) TFR(29) TFR(16) TFR(24)  a += k2; b += k0 + 2u;
  TFR(13) TFR(15) TFR(26) TFR(6)   a += k0; b += k1 + 3u;
  TFR(17) TFR(29) TFR(16) TFR(24)  a += k1; b += k2 + 4u;
  TFR(13) TFR(15) TFR(26) TFR(6)   a += k2; b += k0 + 5u;
#undef TFR
}

// bits -> uniform[-0.99999994, 1) -> sqrt(2)*erfinv(u)  (XLA/Giles erfinv).
// Values bit-identical to R5-R12; slow path now wave-uniformly skipped when
// no lane needs it (P(lane slow) ~ 0.34% -> ~80% of waves skip).
__device__ __forceinline__ float gauss_from_bits(uint32_t bits) {
  const float lo = __uint_as_float(0xBF7FFFFFu);   // nextafter(-1,0)
  float f = __uint_as_float((bits >> 9) | 0x3F800000u) - 1.0f;  // [0,1)
  float u = fmaxf(lo, fmaf(f, 2.0f, lo));
  float om = fmaf(u, -u, 1.0f);                    // 1-u^2 > 0
  float L = __log2f(om);                           // w = -ln2 * L
  // fast path (w < 5), always computed
  float z = fmaf(-0.69314718f, L, -2.5f);          // w - 2.5
  float p =          2.81022636e-08f;
  p = fmaf(p, z, 3.43273939e-07f);
  p = fmaf(p, z, -3.5233877e-06f);
  p = fmaf(p, z, -4.39150654e-06f);
  p = fmaf(p, z, 0.00021858087f);
  p = fmaf(p, z, -0.00125372503f);
  p = fmaf(p, z, -0.00417768164f);
  p = fmaf(p, z, 0.246640727f);
  p = fmaf(p, z, 1.50140941f);
  if (__builtin_expect(__any(L <= -7.2134752f), 0)) {   // some lane: w >= 5
    float zs = sqrtf(-0.69314718f * L) - 3.0f;
    float ps =          -0.000200214257f;
    ps = fmaf(ps, zs, 0.000100950558f);
    ps = fmaf(ps, zs, 0.00134934322f);
    ps = fmaf(ps, zs, -0.00367342844f);
    ps = fmaf(ps, zs, 0.00573950773f);
    ps = fmaf(ps, zs, -0.0076224613f);
    ps = fmaf(ps, zs, 0.00943887047f);
    ps = fmaf(ps, zs, 1.00167406f);
    ps = fmaf(ps, zs, 2.83297682f);
    p = (L > -7.2134752f) ? p : ps;
  }
  return 1.41421356f * (p * u);   // sqrt(2) * erfinv(u)
}

// packed pair f32x2 -> 2 x fp8 e4m3 bytes in bits [15:0] (RNE, saturating)
__device__ __forceinline__ uint32_t f2fp8_pk(float lo_v, float hi_v) {
  return (uint32_t)__builtin_amdgcn_cvt_pk_fp8_f32(lo_v, hi_v, 0, false);
}

// --------------------------------------------------------------------------
// Pre-pass 1: Wx (rows 0..511 of W) -> fp8 e4m3 blob, UNPADDED [c][n][32]
// bytes: chunk c holds k in [32c,32c+32); B-frag for (c,n,q) = 8 B at
// c*16384 + n*32 + q*8.
// --------------------------------------------------------------------------
__global__ void prep_w_kernel(const float* __restrict__ W, uint8_t* __restrict__ blob) {
  int id = blockIdx.x * 256 + threadIdx.x;
  if (id >= 512 * 512) return;
  int k = id >> 9;        // feature (K) index
  int n = id & 511;       // output col
  float v = W[k * 512 + n];
  int c = k >> 5, kk = k & 31;
  blob[c * 16384 + n * 32 + kk] = (uint8_t)f2fp8_pk(v, v);
}

// Pre-pass 2: csum[n] = sum_j W[512+j][n]  (rank-1 t-embedding part)
__global__ void prep_csum_kernel(const float* __restrict__ W, float* __restrict__ csum) {
  int n = blockIdx.x * 256 + threadIdx.x;
  if (n >= 512) return;
  float s = 0.0f;
  for (int j = 0; j < 512; ++j) s += W[(512 + j) * 512 + n];
  csum[n] = s;
}

// --------------------------------------------------------------------------
// Main fused kernel. MFMA 16x16x32 fp8_fp8: A[m=lane&15][k=q*8+j] (from xs,
// 8 B/lane), B[k][n=lane&15] (direct global 8 B coalesced load), C row=4q+reg
// (same C layout as bf16 16x16x32). Block owns rows [64b, 64b+64): mt 0..3;
// wave w covers cols [32w,32w+32): nt in {0,1}, two sequential K-sweeps with
// RNG interleaved (element (mt=c>>2, j=c&3) per c). xs double-buffered,
// 1 barrier/step. W prefetch: rolling depth-2, t-invariant periodic stream.
// --------------------------------------------------------------------------
__global__ __launch_bounds__(1024, 4) void diffuse_kernel(
    const float* __restrict__ x0, const uint8_t* __restrict__ wblob,
    const float* __restrict__ csum, const float* __restrict__ bvec,
    float* __restrict__ out) {
  __shared__ alignas(16) uint8_t xs[2][64 * XS_STRIDE];  // 2 x 33792 B
  __shared__ alignas(8) float2 cb[512];                  // 4096 B {csum, bias}

  const int tid = threadIdx.x;
  const int l15 = tid & 15;
  const int q   = (tid >> 4) & 3;
  const int wv  = tid >> 6;        // wave 0..15
  const int blk = blockIdx.x;      // 0..511

  if (tid < 512) cb[tid] = make_float2(csum[tid], bvec[tid]);

  int ncol[2];
#pragma unroll
  for (int nt = 0; nt < 2; ++nt)
    ncol[nt] = wv * 32 + nt * 16 + l15;

  // fp32 master of x, C-layout: (mt,nt)[j] = local row 16mt+4q+j, col ncol[nt]
  f32x4 xr[4][2];
#pragma unroll
  for (int mt = 0; mt < 4; ++mt)
#pragma unroll
    for (int j = 0; j < 4; ++j) {
      int gr = blk * 64 + mt * 16 + q * 4 + j;
#pragma unroll
      for (int nt = 0; nt < 2; ++nt)
        xr[mt][nt][j] = x0[gr * 512 + ncol[nt]];
    }

  // initial fp8 image into buffer 0 (packed pairs -> 2 byte stores)
#pragma unroll
  for (int mt = 0; mt < 4; ++mt)
#pragma unroll
    for (int nt = 0; nt < 2; ++nt)
#pragma unroll
      for (int jj = 0; jj < 2; ++jj) {
        int m = mt * 16 + q * 4 + jj * 2;
        uint32_t pk = f2fp8_pk(xr[mt][nt][jj * 2], xr[mt][nt][jj * 2 + 1]);
        xs[0][m * XS_STRIDE + ncol[nt]] = (uint8_t)pk;
        xs[0][(m + 1) * XS_STRIDE + ncol[nt]] = (uint8_t)(pk >> 8);
      }

  const float sq2b = sqrtf(0.02f);   // sqrt(2*beta)
  const f32x4 vzero = {0.0f, 0.0f, 0.0f, 0.0f};

  // W fragment bases per column half (bytes); chunk stride 16384 B; stream
  // is periodic (nt0 c0..15, nt1 c0..15, repeat) with t-invariant addresses.
  const uint8_t* wb[2] = {wblob + ncol[0] * 32 + q * 8,
                          wblob + ncol[1] * 32 + q * 8};
  // rolling depth-2 prefetch: bf0/bf1 = chunks 0,1 of the upcoming sweep
  uint64_t bf0 = *(const uint64_t*)(wb[0]);
  uint64_t bf1 = *(const uint64_t*)(wb[0] + 16384);

  __syncthreads();   // init image + cb visible to all waves
  const float2 cbv0 = cb[ncol[0]];
  const float2 cbv1 = cb[ncol[1]];

  for (int t = 0; t < NSTEP; ++t) {
    const uint8_t* xsc = xs[t & 1];
    uint8_t* xsn = xs[(t + 1) & 1];

    // key_t = fold_in(key(42), t) = threefry((0,42),(0,t))  [uniform -> SALU]
    uint32_t kt0 = 0u, kt1 = (uint32_t)t;
    tf_rounds(0u, 42u, 42u ^ 0x1BD11BDAu, kt0, kt1);
    const uint32_t kk2 = kt0 ^ kt1 ^ 0x1BD11BDAu;
    const float tf = (float)t;

#pragma unroll
    for (int nt = 0; nt < 2; ++nt) {
      f32x4 acc[4];
#pragma unroll
      for (int mt = 0; mt < 4; ++mt) acc[mt] = vzero;

      // global element base for this half: row (blk*64 + q*4), col ncol[nt]
      const uint32_t base_e = (uint32_t)((blk * 64 + q * 4) * 512 + ncol[nt]);

      // ---- K sweep with RNG interleave: iteration c does
      //        1 W prefetch (8 B, depth-2, wraps into next sweep)
      //        4 ds_read_b64 + 4 MFMA (consume bf0)
      //        threefry+erfinv for element (mt=c>>2, j=c&3); xr += s*noise --
#pragma unroll
      for (int c = 0; c < 16; ++c) {
        const uint8_t* pp = (c < 14) ? (wb[nt] + (c + 2) * 16384)
                                     : (wb[nt ^ 1] + (c - 14) * 16384);
        uint64_t bf2 = *(const uint64_t*)pp;
#pragma unroll
        for (int mt = 0; mt < 4; ++mt) {
          uint64_t af = *(const uint64_t*)&xsc[(mt * 16 + l15) * XS_STRIDE + c * 32 + q * 8];
          acc[mt] = __builtin_amdgcn_mfma_f32_16x16x32_fp8_fp8(
              (long)af, (long)bf0, acc[mt], 0, 0, 0);
        }
        {
          const int mt_e = c >> 2, j = c & 3;
          uint32_t a = 0u, b = base_e + (uint32_t)(mt_e * 16 * 512 + j * 512);
          tf_rounds(kt0, kt1, kk2, a, b);
          float n = gauss_from_bits(a ^ b);
          xr[mt_e][nt][j] = fmaf(sq2b, n, xr[mt_e][nt][j]);   // x + s*noise
        }
        bf0 = bf1;
        bf1 = bf2;
      }

      // ---- short update: x += B*(acc + t*csum + b), pack, write image ----
      const float2 cbv = nt ? cbv1 : cbv0;
      const float tc = fmaf(tf, cbv.x, cbv.y);
#pragma unroll
      for (int mt = 0; mt < 4; ++mt) {
#pragma unroll
        for (int j = 0; j < 4; ++j)
          xr[mt][nt][j] = fmaf(0.01f, acc[mt][j] + tc, xr[mt][nt][j]);
        if (t + 1 < NSTEP) {
#pragma unroll
          for (int jj = 0; jj < 2; ++jj) {
            int m = mt * 16 + q * 4 + jj * 2;
            uint32_t pk = f2fp8_pk(xr[mt][nt][jj * 2], xr[mt][nt][jj * 2 + 1]);
            xsn[m * XS_STRIDE + ncol[nt]] = (uint8_t)pk;
            xsn[(m + 1) * XS_STRIDE + ncol[nt]] = (uint8_t)(pk >> 8);
          }
        }
      }
    }

    if (t + 1 < NSTEP) __syncthreads();
  }

  // final store (fp32)
#pragma unroll
  for (int mt = 0; mt < 4; ++mt)
#pragma unroll
    for (int j = 0; j < 4; ++j) {
      int gr = blk * 64 + mt * 16 + q * 4 + j;
#pragma unroll
      for (int nt = 0; nt < 2; ++nt)
        out[gr * 512 + ncol[nt]] = xr[mt][nt][j];
    }
}

extern "C" void kernel_launch(void* const* d_in, const int* in_sizes, int n_in,
                              void* d_out, int out_size, void* d_ws, size_t ws_size,
                              hipStream_t stream) {
  const float* x0 = (const float*)d_in[0];   // (32768, 512)
  const float* W  = (const float*)d_in[1];   // (1024, 512)
  const float* bv = (const float*)d_in[2];   // (512,)
  float* out = (float*)d_out;

  uint8_t* blob = (uint8_t*)d_ws;                       // 256 KB fp8 W-blob
  float* csum = (float*)((char*)d_ws + 16 * 16384 * 2); // same 512 KB offset
                                                        // as before (ws safe)

  prep_w_kernel<<<dim3(1024), dim3(256), 0, stream>>>(W, blob);
  prep_csum_kernel<<<dim3(2), dim3(256), 0, stream>>>(W, csum);
  diffuse_kernel<<<dim3(512), dim3(1024), 0, stream>>>(x0, blob, csum, bv, out);
}